// Round 9
// baseline (117.893 us; speedup 1.0000x reference)
//
#include <hip/hip_runtime.h>
#include <hip/hip_bf16.h>
#include <math.h>

// Problem: x (64, 2, 512, 512) f32. x0 = x[:,0] -> (64,512,512).
// n[v] = sqrt(sum_{b,f} x0[b,v,f]^2)
// out[b,i,j] = (sum_f x0[b,i,f]*x0[b,j,f]) / (n[i]*n[j])

#define BATCH 64
#define VDIM 512
#define FDIM 512
#define XBS (2 * VDIM * FDIM)      // x batch stride in floats (T=2)
#define OBS (VDIM * VDIM)          // out batch stride in floats
#define VF (VDIM * FDIM)

typedef __bf16 bf16x8 __attribute__((ext_vector_type(8)));
typedef __bf16 bf16x4 __attribute__((ext_vector_type(4)));
typedef float f32x4 __attribute__((ext_vector_type(4)));

#define BM 128
#define BK 64                      // bf16 elems per K-step

// ws layout: [0, 33554432): bf16 x0 copy; then f32 nsq[512]; u32 slabflag[64]; u32 ncnt
#define NSQ_OFF 33554432
#define FLAG_OFF (NSQ_OFF + 2048)
#define NCNT_OFF (FLAG_OFF + 256)

// global -> LDS direct copy, 16B per lane (dest is wave-uniform base + lane*16)
#define GLL16(g, l)                                                          \
    __builtin_amdgcn_global_load_lds(                                        \
        (const __attribute__((address_space(1))) void*)(g),                  \
        (__attribute__((address_space(3))) void*)(l), 16, 0, 0)

// One kernel, 1280 blocks x 256 threads.
//   blocks 0..255   : producers. Each converts 4 slabs (32 rows each) f32->bf16
//                     into ws, batch-progressive (item t covers batches 16t..16t+15),
//                     accumulates nsq via device-scope atomics, releases slabflag.
//   blocks 256..1279: consumers. Block c-256 = (batch, tile). Acquire-spin until
//                     its batch's 16 slabs are released, then R2-structure gram.
//                     Epilogue acquires ncnt==256, scales by rsqrt(nsq).
__global__ __launch_bounds__(256) void fused_kernel(const float* __restrict__ x,
                                                    __bf16* __restrict__ ws,
                                                    float* __restrict__ nsq,
                                                    unsigned* __restrict__ slabflag,
                                                    unsigned* __restrict__ ncnt,
                                                    float* __restrict__ out) {
    __shared__ __bf16 As[BM * BK];   // 16 KB
    __shared__ __bf16 Bs[BM * BK];

    const int bid = blockIdx.x;
    const int tid = threadIdx.x;

    // ================= producers =================
    if (bid < 256) {
        const int r = tid >> 3;       // 0..31 local row (8 threads per row)
        const int seg = tid & 7;      // 0..7
        #pragma unroll
        for (int t = 0; t < 4; ++t) {
            const int slab = t * 256 + bid;        // batch-progressive order
            const int b = slab >> 4;
            const int g = slab & 15;
            const f32x4* src = (const f32x4*)(x + (size_t)b * XBS + (size_t)(g * 32) * FDIM);
            bf16x4* dst = (bf16x4*)(ws + (size_t)b * VF + (size_t)(g * 32) * FDIM);
            float s = 0.f;
            #pragma unroll
            for (int k = 0; k < 16; ++k) {
                int c = r * 128 + seg + k * 8;     // row r, 128 f32x4 per row
                f32x4 d = src[c];
                s += d[0] * d[0] + d[1] * d[1] + d[2] * d[2] + d[3] * d[3];
                bf16x4 p;
                p[0] = (__bf16)d[0]; p[1] = (__bf16)d[1];
                p[2] = (__bf16)d[2]; p[3] = (__bf16)d[3];
                dst[c] = p;
            }
            s += __shfl_xor(s, 1, 64);
            s += __shfl_xor(s, 2, 64);
            s += __shfl_xor(s, 4, 64);
            if (seg == 0) atomicAdd(&nsq[g * 32 + r], s);   // device-scope
            __syncthreads();   // all stores of this slab issued & drained
            if (tid == 0)
                __hip_atomic_fetch_add(&slabflag[b], 1u, __ATOMIC_RELEASE,
                                       __HIP_MEMORY_SCOPE_AGENT);
        }
        if (tid == 0)
            __hip_atomic_fetch_add(ncnt, 1u, __ATOMIC_RELEASE,
                                   __HIP_MEMORY_SCOPE_AGENT);
        return;
    }

    // ================= consumers =================
    const int c = bid - 256;
    const int batch = c >> 4;
    const int tile = c & 15;
    const int ti = tile >> 2;
    const int tj = tile & 3;

    // wait for this batch's 16 slabs (acquire: invalidates L1/L2 for ws reads)
    if (tid == 0) {
        int fuse = 1 << 24;
        while (__hip_atomic_load(&slabflag[batch], __ATOMIC_ACQUIRE,
                                 __HIP_MEMORY_SCOPE_AGENT) < 16u && --fuse)
            __builtin_amdgcn_s_sleep(8);
    }
    __syncthreads();

    const __bf16* xbb = ws + (size_t)batch * VF;
    const int lane = tid & 63;
    const int wave = tid >> 6;     // 0..3
    const int wr = wave >> 1;      // 0..1
    const int wc = wave & 1;       // 0..1

    // staging addresses: chunk c2 = it*256 + tid: row = c2>>3, cc = c2&7
    // LDS chunk (row,cc) holds global 16B-chunk (row, cc ^ (row&7))  [both-sides XOR]
    const __bf16* gA[4];
    const __bf16* gB[4];
    __bf16* la[4];
    __bf16* lb[4];
    #pragma unroll
    for (int it = 0; it < 4; ++it) {
        int c2 = it * 256 + tid;
        int row = c2 >> 3;
        int cs = (c2 & 7) ^ (row & 7);
        gA[it] = xbb + (size_t)(ti * BM + row) * FDIM + cs * 8;
        gB[it] = xbb + (size_t)(tj * BM + row) * FDIM + cs * 8;
        la[it] = &As[c2 * 8];
        lb[it] = &Bs[c2 * 8];
    }

    // fragment LDS byte offsets: element (r, k=ks*32+(lane>>4)*8) at chunk
    // (r, (ks*4+(lane>>4)) ^ (r&7))
    int offA[2][4], offB[2][4];
    #pragma unroll
    for (int ks = 0; ks < 2; ++ks) {
        #pragma unroll
        for (int m = 0; m < 4; ++m) {
            int rA = wr * 64 + m * 16 + (lane & 15);
            int rB = wc * 64 + m * 16 + (lane & 15);
            int gch = ks * 4 + (lane >> 4);
            offA[ks][m] = rA * (BK * 2) + ((gch ^ (rA & 7)) * 16);
            offB[ks][m] = rB * (BK * 2) + ((gch ^ (rB & 7)) * 16);
        }
    }

    f32x4 acc[4][4];
    #pragma unroll
    for (int m = 0; m < 4; ++m)
        #pragma unroll
        for (int n = 0; n < 4; ++n)
            acc[m][n] = (f32x4){0.f, 0.f, 0.f, 0.f};

    for (int kk = 0; kk < FDIM; kk += BK) {
        #pragma unroll
        for (int it = 0; it < 4; ++it) {
            GLL16(gA[it] + kk, la[it]);
            GLL16(gB[it] + kk, lb[it]);
        }
        __syncthreads();

        #pragma unroll
        for (int ks = 0; ks < 2; ++ks) {
            bf16x8 af[4], bfr[4];
            #pragma unroll
            for (int m = 0; m < 4; ++m) {
                af[m]  = *(const bf16x8*)((const char*)As + offA[ks][m]);
                bfr[m] = *(const bf16x8*)((const char*)Bs + offB[ks][m]);
            }
            #pragma unroll
            for (int m = 0; m < 4; ++m)
                #pragma unroll
                for (int n = 0; n < 4; ++n)
                    acc[m][n] = __builtin_amdgcn_mfma_f32_16x16x32_bf16(af[m], bfr[n], acc[m][n], 0, 0, 0);
        }
        __syncthreads();
    }

    // wait for all nsq contributions (producers are long done by now)
    if (tid == 0) {
        int fuse = 1 << 24;
        while (__hip_atomic_load(ncnt, __ATOMIC_ACQUIRE,
                                 __HIP_MEMORY_SCOPE_AGENT) < 256u && --fuse)
            __builtin_amdgcn_s_sleep(8);
    }
    __syncthreads();

    // epilogue: scale by rsqrt(nsq[i])*rsqrt(nsq[j]), store
    const int rowbase = ti * BM + wr * 64;
    const int colbase = tj * BM + wc * 64;
    float* ob = out + (size_t)batch * OBS;

    float si[16];
    #pragma unroll
    for (int m = 0; m < 4; ++m)
        #pragma unroll
        for (int q = 0; q < 4; ++q)
            si[m * 4 + q] = rsqrtf(nsq[rowbase + m * 16 + (lane >> 4) * 4 + q]);

    #pragma unroll
    for (int n = 0; n < 4; ++n) {
        int j = colbase + n * 16 + (lane & 15);
        float sj = rsqrtf(nsq[j]);
        #pragma unroll
        for (int m = 0; m < 4; ++m) {
            #pragma unroll
            for (int q = 0; q < 4; ++q) {
                int i = rowbase + m * 16 + (lane >> 4) * 4 + q;
                ob[(size_t)i * VDIM + j] = acc[m][n][q] * si[m * 4 + q] * sj;
            }
        }
    }
}

extern "C" void kernel_launch(void* const* d_in, const int* in_sizes, int n_in,
                              void* d_out, int out_size, void* d_ws, size_t ws_size,
                              hipStream_t stream) {
    const float* x = (const float*)d_in[0];
    float* out = (float*)d_out;
    __bf16* ws = (__bf16*)d_ws;
    float* nsq = (float*)((char*)d_ws + NSQ_OFF);
    unsigned* slabflag = (unsigned*)((char*)d_ws + FLAG_OFF);
    unsigned* ncnt = (unsigned*)((char*)d_ws + NCNT_OFF);

    // zero nsq + flags + counter each launch (deterministic; capture-legal)
    hipMemsetAsync(nsq, 0, 2560, stream);
    fused_kernel<<<1280, 256, 0, stream>>>(x, ws, nsq, slabflag, ncnt, out);
}

// Round 10
// 54.632 us; speedup vs baseline: 2.1579x; 2.1579x over previous
//
#include <hip/hip_runtime.h>
#include <hip/hip_bf16.h>
#include <math.h>

// Problem: x (64, 2, 512, 512) f32. x0 = x[:,0] -> (64,512,512).
// n[v] = sqrt(sum_{b,f} x0[b,v,f]^2)
// out[b,i,j] = (sum_f x0[b,i,f]*x0[b,j,f]) / (n[i]*n[j])

#define BATCH 64
#define VDIM 512
#define FDIM 512
#define XBS (2 * VDIM * FDIM)      // x batch stride in floats (T=2)
#define OBS (VDIM * VDIM)          // out batch stride in floats

typedef __bf16 bf16x8 __attribute__((ext_vector_type(8)));
typedef __bf16 bf16x4 __attribute__((ext_vector_type(4)));
typedef float f32x4 __attribute__((ext_vector_type(4)));

#define BM 128
#define BK 64                      // bf16 elems per K-step

// ws layout: [0, 33554432): bf16 x0 copy (64*512*512); then f32 inv_n[512]
#define INVN_OFF 33554432

// global -> LDS direct copy, 16B per lane (dest is wave-uniform base + lane*16)
#define GLL16(g, l)                                                          \
    __builtin_amdgcn_global_load_lds(                                        \
        (const __attribute__((address_space(1))) void*)(g),                  \
        (__attribute__((address_space(3))) void*)(l), 16, 0, 0)

// ---------------- fused norm + bf16-convert kernel: one block per v ----------------
__global__ __launch_bounds__(512) void cvt_norm_kernel(const float* __restrict__ x,
                                                       __bf16* __restrict__ xb,
                                                       float* __restrict__ inv_n) {
    const int v = blockIdx.x;
    const int tid = threadIdx.x;
    float s = 0.f;
    const float4* xf4 = (const float4*)x;
    // 64 batches x 128 float4 per (b, v) row
    for (int c = tid; c < 8192; c += 512) {
        int b = c >> 7;
        int f4 = c & 127;
        float4 d = xf4[(size_t)b * (XBS / 4) + (size_t)v * (FDIM / 4) + f4];
        s += d.x * d.x + d.y * d.y + d.z * d.z + d.w * d.w;
        bf16x4 p;
        p[0] = (__bf16)d.x; p[1] = (__bf16)d.y; p[2] = (__bf16)d.z; p[3] = (__bf16)d.w;
        *(bf16x4*)&xb[(size_t)b * (VDIM * FDIM) + (size_t)v * FDIM + f4 * 4] = p;
    }
    #pragma unroll
    for (int off = 32; off > 0; off >>= 1) s += __shfl_down(s, off, 64);
    __shared__ float partial[8];
    if ((tid & 63) == 0) partial[tid >> 6] = s;
    __syncthreads();
    if (tid == 0) {
        float t = 0.f;
        #pragma unroll
        for (int w = 0; w < 8; ++w) t += partial[w];
        inv_n[v] = 1.0f / sqrtf(t);
    }
}

// ---------------- gram kernel: bf16 global_load_lds + swizzled LDS ----------------
__global__ __launch_bounds__(256) void gram_kernel(const __bf16* __restrict__ xb,
                                                   const float* __restrict__ inv_n,
                                                   float* __restrict__ out) {
    __shared__ __bf16 As[BM * BK];   // 16 KB, linear [128][64] (+XOR swizzle via src)
    __shared__ __bf16 Bs[BM * BK];

    // 64 batches x 16 tiles = 1024 blocks
    // XCD chunked swizzle: 1024 / 8 = 128 contiguous logical wgs per XCD (8 batches)
    const int bid = blockIdx.x;
    const int wg = (bid & 7) * 128 + (bid >> 3);
    const int batch = wg >> 4;
    const int tile = wg & 15;
    const int ti = tile >> 2;
    const int tj = tile & 3;

    const __bf16* xbb = xb + (size_t)batch * (VDIM * FDIM);
    const int tid = threadIdx.x;
    const int lane = tid & 63;
    const int wave = tid >> 6;     // 0..3
    const int wr = wave >> 1;      // 0..1
    const int wc = wave & 1;       // 0..1

    // ---- staging addresses (constant per thread; only kk advances) ----
    // chunk c = it*256 + tid in [0,1024): row = c>>3, cc = c&7
    // LDS chunk (row,cc) holds global 16B-chunk (row, cc ^ (row&7))  [both-sides XOR]
    const __bf16* gA[4];
    const __bf16* gB[4];
    __bf16* la[4];
    __bf16* lb[4];
    #pragma unroll
    for (int it = 0; it < 4; ++it) {
        int c = it * 256 + tid;
        int row = c >> 3;
        int cs = (c & 7) ^ (row & 7);
        gA[it] = xbb + (size_t)(ti * BM + row) * FDIM + cs * 8;
        gB[it] = xbb + (size_t)(tj * BM + row) * FDIM + cs * 8;
        la[it] = &As[c * 8];
        lb[it] = &Bs[c * 8];
    }

    // ---- fragment LDS byte offsets (constant per lane) ----
    // element (r, k=ks*32+(lane>>4)*8) lives at LDS chunk (r, (ks*4+(lane>>4)) ^ (r&7))
    int offA[2][4], offB[2][4];
    #pragma unroll
    for (int ks = 0; ks < 2; ++ks) {
        #pragma unroll
        for (int m = 0; m < 4; ++m) {
            int rA = wr * 64 + m * 16 + (lane & 15);
            int rB = wc * 64 + m * 16 + (lane & 15);
            int gch = ks * 4 + (lane >> 4);
            offA[ks][m] = rA * (BK * 2) + ((gch ^ (rA & 7)) * 16);
            offB[ks][m] = rB * (BK * 2) + ((gch ^ (rB & 7)) * 16);
        }
    }

    f32x4 acc[4][4];
    #pragma unroll
    for (int m = 0; m < 4; ++m)
        #pragma unroll
        for (int n = 0; n < 4; ++n)
            acc[m][n] = (f32x4){0.f, 0.f, 0.f, 0.f};

    for (int kk = 0; kk < FDIM; kk += BK) {
        #pragma unroll
        for (int it = 0; it < 4; ++it) {
            GLL16(gA[it] + kk, la[it]);
            GLL16(gB[it] + kk, lb[it]);
        }
        __syncthreads();   // compiler emits vmcnt(0) drain before barrier

        #pragma unroll
        for (int ks = 0; ks < 2; ++ks) {
            bf16x8 af[4], bfr[4];
            #pragma unroll
            for (int m = 0; m < 4; ++m) {
                af[m]  = *(const bf16x8*)((const char*)As + offA[ks][m]);
                bfr[m] = *(const bf16x8*)((const char*)Bs + offB[ks][m]);
            }
            #pragma unroll
            for (int m = 0; m < 4; ++m)
                #pragma unroll
                for (int n = 0; n < 4; ++n)
                    acc[m][n] = __builtin_amdgcn_mfma_f32_16x16x32_bf16(af[m], bfr[n], acc[m][n], 0, 0, 0);
        }
        __syncthreads();
    }

    // ---- epilogue: scale by inv_n[i]*inv_n[j]; nt stores (out is never re-read:
    //      evict-first in L2 so the ws panels stay resident for other tiles) ----
    const int rowbase = ti * BM + wr * 64;
    const int colbase = tj * BM + wc * 64;
    float* ob = out + (size_t)batch * OBS;

    float si[16];
    #pragma unroll
    for (int m = 0; m < 4; ++m)
        #pragma unroll
        for (int q = 0; q < 4; ++q)
            si[m * 4 + q] = inv_n[rowbase + m * 16 + (lane >> 4) * 4 + q];

    #pragma unroll
    for (int n = 0; n < 4; ++n) {
        int j = colbase + n * 16 + (lane & 15);
        float sj = inv_n[j];
        #pragma unroll
        for (int m = 0; m < 4; ++m) {
            #pragma unroll
            for (int q = 0; q < 4; ++q) {
                int i = rowbase + m * 16 + (lane >> 4) * 4 + q;
                __builtin_nontemporal_store(acc[m][n][q] * si[m * 4 + q] * sj,
                                            &ob[(size_t)i * VDIM + j]);
            }
        }
    }
}

extern "C" void kernel_launch(void* const* d_in, const int* in_sizes, int n_in,
                              void* d_out, int out_size, void* d_ws, size_t ws_size,
                              hipStream_t stream) {
    const float* x = (const float*)d_in[0];
    float* out = (float*)d_out;
    __bf16* xbf = (__bf16*)d_ws;
    float* inv_n = (float*)((char*)d_ws + INVN_OFF);

    cvt_norm_kernel<<<VDIM, 512, 0, stream>>>(x, xbf, inv_n);
    gram_kernel<<<BATCH * 16, 256, 0, stream>>>(xbf, inv_n, out);
}